// Round 1
// baseline (85.401 us; speedup 1.0000x reference)
//
#include <hip/hip_runtime.h>
#include <cfloat>

// Chamfer L1: pred [B,N,3], gt [B,M,3], fp32.
// out = mean_b( mean_n min_m d(b,n,m) + mean_m min_n d(b,n,m) ),
// d = L1 distance. Strategy: per-direction tiled brute force.
//   - dir 0: query = pred, target = gt   (min over m for each n)
//   - dir 1: query = gt,   target = pred (min over n for each m)
// ws holds per-query-point running mins (float, compared via int atomicMin
// — valid because distances are non-negative so IEEE order == int order).

constexpr int MC  = 512;   // target points staged in LDS per block
constexpr int NC  = 512;   // query points per block (2 per thread)
constexpr int TPB = 256;

__global__ __launch_bounds__(256) void init_min_kernel(float* wsmin, int n) {
    int i = blockIdx.x * blockDim.x + threadIdx.x;
    if (i < n) wsmin[i] = FLT_MAX;
}

__global__ __launch_bounds__(TPB) void chamfer_min_kernel(
    const float* __restrict__ pred, const float* __restrict__ gt,
    float* __restrict__ wsmin, int B, int N, int M) {
    const int dir = blockIdx.z;
    const int b   = blockIdx.y;
    const float* q  = dir ? gt   : pred;   // query cloud
    const float* t  = dir ? pred : gt;     // target cloud
    const int Nq    = dir ? M : N;
    const int Nt    = dir ? N : M;
    const int nchunks = Nq / NC;
    const int nc = blockIdx.x % nchunks;
    const int mc = blockIdx.x / nchunks;

    __shared__ float4 lds4[MC];

    // Stage target chunk into LDS as float4 (w unused) for ds_read_b128.
    const float* tbase = t + ((size_t)b * Nt + (size_t)mc * MC) * 3;
    for (int i = threadIdx.x; i < MC * 3; i += TPB) {
        int m = i / 3, c = i % 3;
        ((float*)&lds4[m])[c] = tbase[i];
    }
    __syncthreads();

    // Two query points per thread, held in registers.
    const int n0 = nc * NC + threadIdx.x;
    const int n1 = n0 + TPB;
    const float* qb = q + (size_t)b * Nq * 3;
    const float p0x = qb[n0 * 3 + 0], p0y = qb[n0 * 3 + 1], p0z = qb[n0 * 3 + 2];
    const float p1x = qb[n1 * 3 + 0], p1y = qb[n1 * 3 + 1], p1z = qb[n1 * 3 + 2];

    float m0 = FLT_MAX, m1 = FLT_MAX;
#pragma unroll 8
    for (int j = 0; j < MC; ++j) {
        float4 g = lds4[j];   // broadcast read — all lanes same addr, no conflict
        float d0 = fabsf(p0x - g.x) + fabsf(p0y - g.y) + fabsf(p0z - g.z);
        float d1 = fabsf(p1x - g.x) + fabsf(p1y - g.y) + fabsf(p1z - g.z);
        m0 = fminf(m0, d0);
        m1 = fminf(m1, d1);
    }

    // Combine partial mins across m-chunks. Distances >= 0 so int compare
    // preserves float order.
    float* base = wsmin + (size_t)dir * B * N + (size_t)b * Nq;
    atomicMin((int*)(base + n0), __float_as_int(m0));
    atomicMin((int*)(base + n1), __float_as_int(m1));
}

__global__ __launch_bounds__(1024) void reduce_kernel(
    const float* __restrict__ wsmin, float* __restrict__ out,
    int B, int N, int M) {
    const int tid = threadIdx.x;
    const int total0 = B * N, total1 = B * M;
    float s0 = 0.f, s1 = 0.f;
    for (int i = tid; i < total0; i += 1024) s0 += wsmin[i];
    for (int i = tid; i < total1; i += 1024) s1 += wsmin[total0 + i];
    float v = s0 * (1.0f / (float)total0) + s1 * (1.0f / (float)total1);

    // wave-64 shuffle reduce
    for (int off = 32; off > 0; off >>= 1) v += __shfl_down(v, off, 64);

    __shared__ float red[16];
    const int lane = tid & 63, wave = tid >> 6;
    if (lane == 0) red[wave] = v;
    __syncthreads();
    if (tid == 0) {
        float s = 0.f;
        for (int w = 0; w < 16; ++w) s += red[w];
        out[0] = s;
    }
}

extern "C" void kernel_launch(void* const* d_in, const int* in_sizes, int n_in,
                              void* d_out, int out_size, void* d_ws, size_t ws_size,
                              hipStream_t stream) {
    const float* pred = (const float*)d_in[0];
    const float* gt   = (const float*)d_in[1];
    float* out = (float*)d_out;

    const int B = 4;
    const int N = in_sizes[0] / (B * 3);   // 4096
    const int M = in_sizes[1] / (B * 3);   // 4096

    float* wsmin = (float*)d_ws;           // [2*B*4096] floats = 128 KB
    const int total = B * (N + M);

    init_min_kernel<<<(total + 255) / 256, 256, 0, stream>>>(wsmin, total);

    // dir 0: (N/NC) query-chunks x (M/MC) target-chunks; dir 1 symmetric.
    dim3 grid((N / NC) * (M / MC), B, 2);  // 64 x 4 x 2 = 512 blocks
    chamfer_min_kernel<<<grid, TPB, 0, stream>>>(pred, gt, wsmin, B, N, M);

    reduce_kernel<<<1, 1024, 0, stream>>>(wsmin, out, B, N, M);
}

// Round 2
// 76.234 us; speedup vs baseline: 1.1202x; 1.1202x over previous
//
#include <hip/hip_runtime.h>
#include <cfloat>

// Chamfer L1, pred [B,N,3], gt [B,M,3] fp32, N==M==4096, B==4.
// Kernel 1: per (dir, b, query-chunk, target-chunk) block computes each query's
//           min over the staged target chunk; plain coalesced store of the
//           partial min to ws[mc][dir][b][n]. No atomics, no init pass.
// Kernel 2: min-reduce over the 16 target-chunks per query, scale, block-sum,
//           one float atomicAdd per block into d_out (memset to 0 first).

constexpr int TPB = 256;
constexpr int PTS = 4;            // query points per thread (ILP: 24 VALU per LDS read)
constexpr int NC  = TPB * PTS;    // 1024 queries per block
constexpr int MC  = 256;          // targets staged in LDS per block

__global__ __launch_bounds__(TPB) void chamfer_partial_kernel(
    const float* __restrict__ pred, const float* __restrict__ gt,
    float* __restrict__ partial, int B, int N, int M) {
    const int dir = blockIdx.z;
    const int b   = blockIdx.y;
    const float* q = dir ? gt   : pred;
    const float* t = dir ? pred : gt;
    const int Nq   = dir ? M : N;
    const int Nt   = dir ? N : M;
    const int nchunks = Nq / NC;              // 4
    const int nc = blockIdx.x % nchunks;
    const int mc = blockIdx.x / nchunks;      // 0..Nt/MC-1

    __shared__ float4 lds4[MC];               // w unused; 4 KB

    // Stage target chunk (256 pts x 12 B) into LDS as padded float4.
    const float* tbase = t + ((size_t)b * Nt + (size_t)mc * MC) * 3;
    for (int i = threadIdx.x; i < MC * 3; i += TPB) {
        ((float*)&lds4[i / 3])[i % 3] = tbase[i];
    }
    __syncthreads();

    // 4 query points per thread, in registers.
    const float* qb = q + (size_t)b * Nq * 3;
    float px[PTS], py[PTS], pz[PTS], mn[PTS];
    int n[PTS];
#pragma unroll
    for (int i = 0; i < PTS; ++i) {
        n[i] = nc * NC + threadIdx.x + i * TPB;
        px[i] = qb[n[i] * 3 + 0];
        py[i] = qb[n[i] * 3 + 1];
        pz[i] = qb[n[i] * 3 + 2];
        mn[i] = FLT_MAX;
    }

#pragma unroll 8
    for (int j = 0; j < MC; ++j) {
        float4 g = lds4[j];   // broadcast ds_read_b128 — all lanes same addr
#pragma unroll
        for (int i = 0; i < PTS; ++i) {
            float d = fabsf(px[i] - g.x) + fabsf(py[i] - g.y) + fabsf(pz[i] - g.z);
            mn[i] = fminf(mn[i], d);
        }
    }

    // partial[mc][dir][b][n] — coalesced stores (N==M assumed for stride).
    float* outp = partial + (((size_t)mc * 2 + dir) * B + b) * N;
#pragma unroll
    for (int i = 0; i < PTS; ++i) outp[n[i]] = mn[i];
}

__global__ __launch_bounds__(256) void chamfer_reduce_kernel(
    const float* __restrict__ partial, float* __restrict__ out,
    int Q, int nmc, float inv) {
    const int qidx = blockIdx.x * 256 + threadIdx.x;
    float mn = FLT_MAX;
#pragma unroll
    for (int mc = 0; mc < 16; ++mc)   // nmc == 16 for N==M==4096
        mn = fminf(mn, partial[(size_t)mc * Q + qidx]);
    float v = mn * inv;

    // wave-64 shuffle reduce, then cross-wave via LDS
    for (int off = 32; off > 0; off >>= 1) v += __shfl_down(v, off, 64);
    __shared__ float red[4];
    const int lane = threadIdx.x & 63, w = threadIdx.x >> 6;
    if (lane == 0) red[w] = v;
    __syncthreads();
    if (threadIdx.x == 0)
        atomicAdd(out, red[0] + red[1] + red[2] + red[3]);
}

extern "C" void kernel_launch(void* const* d_in, const int* in_sizes, int n_in,
                              void* d_out, int out_size, void* d_ws, size_t ws_size,
                              hipStream_t stream) {
    const float* pred = (const float*)d_in[0];
    const float* gt   = (const float*)d_in[1];
    float* out = (float*)d_out;

    const int B = 4;
    const int N = in_sizes[0] / (B * 3);   // 4096
    const int M = in_sizes[1] / (B * 3);   // 4096

    float* partial = (float*)d_ws;          // [16][2][B][N] floats = 2 MB
    const int nmc = M / MC;                 // 16
    const int Q = 2 * B * N;                // 32768

    hipMemsetAsync(out, 0, sizeof(float), stream);

    dim3 grid((N / NC) * nmc, B, 2);        // 64 x 4 x 2 = 512 blocks
    chamfer_partial_kernel<<<grid, TPB, 0, stream>>>(pred, gt, partial, B, N, M);

    // mean scale: 1/(B*N) for dir0, 1/(B*M) for dir1 — equal since N==M.
    chamfer_reduce_kernel<<<Q / 256, 256, 0, stream>>>(
        partial, out, Q, nmc, 1.0f / (float)(B * N));
}